// Round 20
// baseline (33.110 us; speedup 1.0000x reference)
//
#include <hip/hip_runtime.h>

// Maj3: out[b,o,h,w] = sum_{kh,c} sign( sum_{kw} x[b,c,h+kh-1,w+kw-1] * W[o,kw,kh,c] )
// x: (4,64,56,56) f32; W: (64,3,3,64) f32; out: (4,64,56,56) f32.
// Bit-exactness vs numpy required (threshold 1.36, integer output): contract(off),
// reference mul/add order per sign. Padded rows staged as 0.0 -> sums are +-0;
// the (s < 0) predicate counts neither, and base=nvalid*64 excludes them.
//
// R20: R19 (one-instr v_cmp ballot) + two issue-efficiency fixes:
//  (a) 1-pixel-ahead DS pipeline: issue pixel P+1's three ds_read_b32 before
//      pixel P's 19-VALU compute -> ~120cyc DS latency off the critical path.
//  (b) SLABP 31->30: LDS 23808->23040 B -> 7 blocks/CU resident (was 6+backfill);
//      grid is exactly 7/CU so all blocks co-start, zero tail. Cost: even
//      stride -> 4-way read bank conflict (~1.58x on LDS pipe), absorbed
//      under VALU time (~9us LDS vs ~14.5us VALU per CU).

#define Cn 64
#define Hn 56
#define Wn 56
#define On 64
#define OG 4        // output channels per wave (proven spill-free budget)
#define PIX 28      // pixels per wave (half row)
#define SLABW 30    // staged taps per row: w0-1 .. w0+28
#define SLABP 30    // stride == width: LDS fits 7 blocks/CU (4-way rd conflict ok)

// v_writelane_b32: write wave-uniform `val` into lane `LANE` of `dst`.
#define WRITELANE(dst, val, LANE)                                             \
    asm("v_writelane_b32 %0, %1, " #LANE                                      \
        : "+v"(dst) : "s"(val))

// One-instruction ballot: mask[lane] = (v < 0.0f). VOP3 v_cmp, SGPR-pair dest,
// inline-constant 0 src1. Non-volatile -> schedulable.
#define BALLOT_LT0(mask, v)                                                   \
    asm("v_cmp_lt_f32 %0, %1, 0" : "=s"(mask) : "v"(v))

__global__ __launch_bounds__(256, 4)
void maj3_kernel(const float* __restrict__ x,
                 const float* __restrict__ wt,
                 float* __restrict__ out)
{
#pragma clang fp contract(off)
    __shared__ float slab[3][Cn][SLABP];

    const int lane  = threadIdx.x & 63;   // = channel c
    const int wave  = __builtin_amdgcn_readfirstlane((int)(threadIdx.x >> 6)); // 0..3
    const int bh    = blockIdx.x;         // 0..223
    const int b     = bh / Hn;
    const int h     = bh - b * Hn;
    const int w0    = blockIdx.y * PIX;   // 0 or 28
    const int obase = blockIdx.z * 16 + wave * OG;   // this wave's o range

    // Stage x[b, :, h-1..h+1, w0-1..w0+28] into slab; pads (rows and cols)
    // staged as exact 0.0f. 5760 elements over 256 threads, once per block.
    const float* xb = x + b * (Cn * Hn * Wn);
    for (int i = threadIdx.x; i < 3 * Cn * SLABW; i += 256) {
        const int ws  = i % SLABW;
        const int t   = i / SLABW;
        const int c   = t & (Cn - 1);
        const int r   = t >> 6;
        const int row = h + r - 1;
        const int w   = w0 - 1 + ws;
        float v = 0.0f;
        if (row >= 0 && row < Hn && (unsigned)w < (unsigned)Wn)
            v = xb[(c * Hn + row) * Wn + w];
        slab[r][c][ws] = v;
    }

    // This wave's weights, lane = c: W[o,kw,kh,c] = wt[((o*3+kw)*3+kh)*64+c].
    // 36 coalesced 256B loads, once; lives in 36 VGPRs for the whole kernel.
    float wreg[OG][3][3];
    #pragma unroll
    for (int oo = 0; oo < OG; ++oo)
        #pragma unroll
        for (int kw = 0; kw < 3; ++kw)
            #pragma unroll
            for (int kh = 0; kh < 3; ++kh)
                wreg[oo][kh][kw] = wt[(((obase + oo) * 3 + kw) * 3 + kh) * Cn + lane];

    __syncthreads();

    int vcnt[OG];                         // lane p holds neg-count for pixel p
    #pragma unroll
    for (int oo = 0; oo < OG; ++oo) vcnt[oo] = 0;

    // Sliding 3-tap windows + 1-pixel-ahead prefetch regs (SSA under unroll).
    float xl[3], xm[3], xn[3];
    #pragma unroll
    for (int r = 0; r < 3; ++r) {
        xl[r] = slab[r][lane][0];
        xm[r] = slab[r][lane][1];
        xn[r] = slab[r][lane][2];         // pixel 0's right tap
    }

#define PBODY(P, PREFETCH)                                                    \
    do {                                                                      \
        float xc[3];                                                          \
        _Pragma("unroll")                                                     \
        for (int r = 0; r < 3; ++r) xc[r] = xn[r];                            \
        if (PREFETCH) {                                                       \
            _Pragma("unroll")                                                 \
            for (int r = 0; r < 3; ++r) xn[r] = slab[r][lane][(P) + 3];       \
        }                                                                     \
        _Pragma("unroll")                                                     \
        for (int oo = 0; oo < OG; ++oo) {                                     \
            int cnt = 0;                                                      \
            _Pragma("unroll")                                                 \
            for (int r = 0; r < 3; ++r) {                                     \
                const float s = (xl[r] * wreg[oo][r][0] +                     \
                                 xm[r] * wreg[oo][r][1])                      \
                              + xc[r] * wreg[oo][r][2];                       \
                unsigned long long m;                                         \
                BALLOT_LT0(m, s);                                             \
                cnt += (int)__builtin_popcountll(m);                          \
            }                                                                 \
            const int cs = __builtin_amdgcn_readfirstlane(cnt);              \
            WRITELANE(vcnt[oo], cs, P);                                       \
        }                                                                     \
        _Pragma("unroll")                                                     \
        for (int r = 0; r < 3; ++r) { xl[r] = xm[r]; xm[r] = xc[r]; }         \
    } while (0)

    PBODY(0,1);  PBODY(1,1);  PBODY(2,1);  PBODY(3,1);  PBODY(4,1);
    PBODY(5,1);  PBODY(6,1);  PBODY(7,1);  PBODY(8,1);  PBODY(9,1);
    PBODY(10,1); PBODY(11,1); PBODY(12,1); PBODY(13,1); PBODY(14,1);
    PBODY(15,1); PBODY(16,1); PBODY(17,1); PBODY(18,1); PBODY(19,1);
    PBODY(20,1); PBODY(21,1); PBODY(22,1); PBODY(23,1); PBODY(24,1);
    PBODY(25,1); PBODY(26,1); PBODY(27,0);

    // out = nvalid*64 - 2*negcount (padded rows excluded; their staged-zero
    // sums are +-0 -> (s<0) false -> never counted).
    const int nvalid = 3 - (h == 0) - (h == Hn - 1);
    const float base = (float)(nvalid * Cn);
    if (lane < PIX) {
        float* ob = out + ((b * On + obase) * Hn + h) * Wn + w0 + lane;
        #pragma unroll
        for (int oo = 0; oo < OG; ++oo)
            ob[oo * Hn * Wn] = base - 2.0f * (float)vcnt[oo];
    }
}

extern "C" void kernel_launch(void* const* d_in, const int* in_sizes, int n_in,
                              void* d_out, int out_size, void* d_ws, size_t ws_size,
                              hipStream_t stream) {
    const float* x  = (const float*)d_in[0];
    const float* wt = (const float*)d_in[1];
    float* o        = (float*)d_out;
    dim3 grid(224, 2, 4);   // (b,h) x w-half x o-quarter; 4 waves x (28px, 4o)
    maj3_kernel<<<grid, dim3(256), 0, stream>>>(x, wt, o);
}

// Round 21
// 27.898 us; speedup vs baseline: 1.1868x; 1.1868x over previous
//
#include <hip/hip_runtime.h>

// Maj3: out[b,o,h,w] = sum_{kh,c} sign( sum_{kw} x[b,c,h+kh-1,w+kw-1] * W[o,kw,kh,c] )
// x: (4,64,56,56) f32; W: (64,3,3,64) f32; out: (4,64,56,56) f32.
// Bit-exactness vs numpy required (threshold 1.36, integer output): contract(off),
// reference mul/add order per sign. Padded rows staged as 0.0 -> sums are +-0;
// the (s < 0) predicate counts neither, and base=nvalid*64 excludes them.
//
// R21: R20's bundle (manual prefetch + even-stride LDS) regressed — reverted.
// New lever on top of R19: fuse TWO h-rows per block. Slab [4][64][17] serves
// h0 and h0+1 (kh windows = slab rows 0-2 and 1-3): shared-row column reads
// CSE in registers (ds_reads 6->4 per 2 outputs), staging per output -29%
// (4096 elems vs 5760 for 448 outputs), pow-2 staging index math (&15 vs %30).
// PIX=14 w-quarters, OG=4 (proven 36-wreg budget), grid (112,4,4) = 1792 =
// exactly 7 blocks/CU; LDS 17.4KB -> 9-resident; cap-128 via (256,4).

#define Cn 64
#define Hn 56
#define Wn 56
#define On 64
#define OG 4        // output channels per wave (proven spill-free budget)
#define PIX 14      // pixels per wave (quarter row)
#define SLABW 16    // staged taps per row: w0-1 .. w0+14 (pow2)
#define SLABP 17    // padded stride (odd -> 2 lanes/bank = conflict-free)

// v_writelane_b32: write wave-uniform `val` into lane `LANE` of `dst`.
#define WRITELANE(dst, val, LANE)                                             \
    asm("v_writelane_b32 %0, %1, " #LANE                                      \
        : "+v"(dst) : "s"(val))

// One-instruction ballot: mask[lane] = (v < 0.0f). VOP3 v_cmp, SGPR-pair dest,
// inline-constant 0 src1. Non-volatile -> schedulable.
#define BALLOT_LT0(mask, v)                                                   \
    asm("v_cmp_lt_f32 %0, %1, 0" : "=s"(mask) : "v"(v))

__global__ __launch_bounds__(256, 4)
void maj3_kernel(const float* __restrict__ x,
                 const float* __restrict__ wt,
                 float* __restrict__ out)
{
#pragma clang fp contract(off)
    __shared__ float slab[4][Cn][SLABP];   // rows h0-1 .. h0+2

    const int lane  = threadIdx.x & 63;    // = channel c
    const int wave  = __builtin_amdgcn_readfirstlane((int)(threadIdx.x >> 6)); // 0..3
    const int b     = blockIdx.x / 28;     // 4 batches x 28 h-pairs
    const int hp    = blockIdx.x - b * 28;
    const int h0    = hp * 2;              // even row; h1 = h0+1 (odd, <=55)
    const int w0    = blockIdx.y * PIX;    // 0,14,28,42
    const int obase = blockIdx.z * 16 + wave * OG;   // this wave's o range

    // Stage x[b, :, h0-1..h0+2, w0-1..w0+14] into slab; pads staged as 0.0f.
    // 4096 elements over 256 threads = 16 iterations, pow-2 index math.
    const float* xb = x + b * (Cn * Hn * Wn);
    for (int i = threadIdx.x; i < 4 * Cn * SLABW; i += 256) {
        const int ws  = i & (SLABW - 1);
        const int t   = i >> 4;
        const int c   = t & (Cn - 1);
        const int r   = t >> 6;            // 0..3
        const int row = h0 + r - 1;
        const int w   = w0 - 1 + ws;
        float v = 0.0f;
        if (row >= 0 && row < Hn && (unsigned)w < (unsigned)Wn)
            v = xb[(c * Hn + row) * Wn + w];
        slab[r][c][ws] = v;
    }

    // This wave's weights, lane = c: W[o,kw,kh,c] = wt[((o*3+kw)*3+kh)*64+c].
    // 36 coalesced 256B loads, once; lives in 36 VGPRs for the whole kernel.
    float wreg[OG][3][3];
    #pragma unroll
    for (int oo = 0; oo < OG; ++oo)
        #pragma unroll
        for (int kw = 0; kw < 3; ++kw)
            #pragma unroll
            for (int kh = 0; kh < 3; ++kh)
                wreg[oo][kh][kw] = wt[(((obase + oo) * 3 + kw) * 3 + kh) * Cn + lane];

    __syncthreads();

    int vcnt[2][OG];                       // lane p: neg-count, rows h0/h1
    #pragma unroll
    for (int ho = 0; ho < 2; ++ho)
        #pragma unroll
        for (int oo = 0; oo < OG; ++oo) vcnt[ho][oo] = 0;

    // Sliding 3-tap windows across 4 slab rows (SSA renames under unroll).
    float xl[4], xm[4];
    #pragma unroll
    for (int r = 0; r < 4; ++r) {
        xl[r] = slab[r][lane][0];
        xm[r] = slab[r][lane][1];
    }

#define PBODY(P)                                                              \
    do {                                                                      \
        float xc[4];                                                          \
        _Pragma("unroll")                                                     \
        for (int r = 0; r < 4; ++r) xc[r] = slab[r][lane][(P) + 2];           \
        _Pragma("unroll")                                                     \
        for (int ho = 0; ho < 2; ++ho) {                                      \
            _Pragma("unroll")                                                 \
            for (int oo = 0; oo < OG; ++oo) {                                 \
                int cnt = 0;                                                  \
                _Pragma("unroll")                                             \
                for (int kh = 0; kh < 3; ++kh) {                              \
                    const float s = (xl[ho + kh] * wreg[oo][kh][0] +          \
                                     xm[ho + kh] * wreg[oo][kh][1])           \
                                  + xc[ho + kh] * wreg[oo][kh][2];            \
                    unsigned long long m;                                     \
                    BALLOT_LT0(m, s);                                         \
                    cnt += (int)__builtin_popcountll(m);                      \
                }                                                             \
                const int cs = __builtin_amdgcn_readfirstlane(cnt);          \
                WRITELANE(vcnt[ho][oo], cs, P);                               \
            }                                                                 \
        }                                                                     \
        _Pragma("unroll")                                                     \
        for (int r = 0; r < 4; ++r) { xl[r] = xm[r]; xm[r] = xc[r]; }         \
    } while (0)

    PBODY(0);  PBODY(1);  PBODY(2);  PBODY(3);  PBODY(4);  PBODY(5);
    PBODY(6);  PBODY(7);  PBODY(8);  PBODY(9);  PBODY(10); PBODY(11);
    PBODY(12); PBODY(13);

    // out = nvalid*64 - 2*negcount. h0 even in [0,54]: pad only when h0==0;
    // h1 odd in [1,55]: pad only when h1==55. Padded slab rows are zero ->
    // their sums are +-0 -> (s<0) never counts them.
    if (lane < PIX) {
        #pragma unroll
        for (int ho = 0; ho < 2; ++ho) {
            const int h = h0 + ho;
            const int nvalid = 3 - (h == 0) - (h == Hn - 1);
            const float base = (float)(nvalid * Cn);
            float* ob = out + ((b * On + obase) * Hn + h) * Wn + w0 + lane;
            #pragma unroll
            for (int oo = 0; oo < OG; ++oo)
                ob[oo * Hn * Wn] = base - 2.0f * (float)vcnt[ho][oo];
        }
    }
}

extern "C" void kernel_launch(void* const* d_in, const int* in_sizes, int n_in,
                              void* d_out, int out_size, void* d_ws, size_t ws_size,
                              hipStream_t stream) {
    const float* x  = (const float*)d_in[0];
    const float* wt = (const float*)d_in[1];
    float* o        = (float*)d_out;
    dim3 grid(112, 4, 4);   // (b,h-pair) x w-quarter x o-quarter
    maj3_kernel<<<grid, dim3(256), 0, stream>>>(x, wt, o);
}